// Round 1
// baseline (6555.554 us; speedup 1.0000x reference)
//
#include <hip/hip_runtime.h>

// Problem constants (MetaBaseline: B,Q,WAY,SHOT,H,W,C = 2,75,5,5,10,10,640; k=5)
#define BQ    2
#define QN    75
#define WAYN  5
#define SHOTN 5
#define HWN   100
#define CN    640
#define NSUP  500                    // WAY*HW support descriptors per (b, group)
#define NQD   (BQ * QN * HWN)        // 15000 query descriptors
#define NSD   (BQ * SHOTN * WAYN * HWN) // 5000 support descriptors
#define NC    25                     // support chunk held in per-lane accumulators

// ---------------------------------------------------------------------------
// Kernel 1: inverse L2 norms of every descriptor (query then support).
// One wave per descriptor; lane i sums elements i, i+64, ... (coalesced).
// ---------------------------------------------------------------------------
__global__ __launch_bounds__(256) void norm_kernel(const float* __restrict__ q,
                                                   const float* __restrict__ s,
                                                   float* __restrict__ qinv,
                                                   float* __restrict__ sinv) {
    int wave = (blockIdx.x * 256 + threadIdx.x) >> 6;
    int lane = threadIdx.x & 63;
    if (wave >= NQD + NSD) return;
    const float* base = (wave < NQD) ? (q + (size_t)wave * CN)
                                     : (s + (size_t)(wave - NQD) * CN);
    float ss = 0.f;
#pragma unroll
    for (int i = 0; i < CN / 64; ++i) {
        float v = base[lane + 64 * i];
        ss = fmaf(v, v, ss);
    }
#pragma unroll
    for (int off = 32; off > 0; off >>= 1)
        ss += __shfl_down(ss, off, 64);
    if (lane == 0) {
        float inv = rsqrtf(ss);
        if (wave < NQD) qinv[wave] = inv;
        else            sinv[wave - NQD] = inv;
    }
}

// ---------------------------------------------------------------------------
// Kernel 2: fused scores + per-patch top-5 + reduction.
// lane = one query patch (global patch id gp); blockIdx.y = class group g.
// Support descriptors are wave-uniform -> scalar loads on the SALU pipe.
// Per-lane: stream supports in chunks of NC, keep running top-5 in registers
// (branchless insertion network), finally atomicAdd mean-of-top5 into out.
// ---------------------------------------------------------------------------
__global__ __launch_bounds__(256) void score_kernel(const float* __restrict__ qd,
                                                    const float* __restrict__ sd,
                                                    const float* __restrict__ qinv,
                                                    const float* __restrict__ sinv,
                                                    float* __restrict__ out) {
    int gp = blockIdx.x * 256 + threadIdx.x;   // global query-patch id
    int g  = blockIdx.y;                       // class group
    if (gp >= NQD) return;

    int b   = gp / (QN * HWN);
    int rem = gp - b * (QN * HWN);
    int qi_idx = rem / HWN;                    // query image index

    const float* aptr  = qd + (size_t)gp * CN;
    // support group (b,g): contiguous 500 descriptors starting at desc index
    // b*2500 + g*500 (input2 [b,shot,way,h,w,c] with group == shot index)
    int sdesc0 = (b * SHOTN + g) * NSUP;
    const float* sbase = sd + (size_t)sdesc0 * CN;
    const float* sivp  = sinv + sdesc0;
    float qscale = qinv[gp];

    float t0 = -3.4e38f, t1 = -3.4e38f, t2 = -3.4e38f, t3 = -3.4e38f, t4 = -3.4e38f;

    for (int jc = 0; jc < NSUP; jc += NC) {
        float acc[NC];
#pragma unroll
        for (int jj = 0; jj < NC; ++jj) acc[jj] = 0.f;

        for (int kc = 0; kc < CN; kc += 4) {
            float4 a4 = *(const float4*)(aptr + kc);
#pragma unroll
            for (int jj = 0; jj < NC; ++jj) {
                const float* sp = sbase + (size_t)(jc + jj) * CN + kc; // uniform
                acc[jj] = fmaf(a4.x, sp[0], acc[jj]);
                acc[jj] = fmaf(a4.y, sp[1], acc[jj]);
                acc[jj] = fmaf(a4.z, sp[2], acc[jj]);
                acc[jj] = fmaf(a4.w, sp[3], acc[jj]);
            }
        }
#pragma unroll
        for (int jj = 0; jj < NC; ++jj) {
            float v = acc[jj] * qscale * sivp[jc + jj];
            // branchless sorted-insert into t0 >= t1 >= ... >= t4
            float hi;
            hi = fmaxf(t0, v); v = fminf(t0, v); t0 = hi;
            hi = fmaxf(t1, v); v = fminf(t1, v); t1 = hi;
            hi = fmaxf(t2, v); v = fminf(t2, v); t2 = hi;
            hi = fmaxf(t3, v); v = fminf(t3, v); t3 = hi;
            hi = fmaxf(t4, v); v = fminf(t4, v); t4 = hi;
        }
    }

    float r = (t0 + t1 + t2 + t3 + t4) * 0.2f;
    atomicAdd(&out[(b * QN + qi_idx) * WAYN + g], r);
}

extern "C" void kernel_launch(void* const* d_in, const int* in_sizes, int n_in,
                              void* d_out, int out_size, void* d_ws, size_t ws_size,
                              hipStream_t stream) {
    const float* in1 = (const float*)d_in[0];   // [2,75,10,10,640] fp32
    const float* in2 = (const float*)d_in[1];   // [2,5,5,10,10,640] fp32
    float* out  = (float*)d_out;                // [2,75,5]
    float* qinv = (float*)d_ws;                 // 15000 floats
    float* sinv = qinv + NQD;                   // 5000 floats

    hipMemsetAsync(d_out, 0, (size_t)out_size * sizeof(float), stream);

    // 20000 descriptors, one wave each, 4 waves per block
    norm_kernel<<<dim3((NQD + NSD) / 4), 256, 0, stream>>>(in1, in2, qinv, sinv);

    dim3 grid((NQD + 255) / 256, WAYN);
    score_kernel<<<grid, 256, 0, stream>>>(in1, in2, qinv, sinv, out);
}

// Round 2
// 630.079 us; speedup vs baseline: 10.4043x; 10.4043x over previous
//
#include <hip/hip_runtime.h>

// MetaBaseline: B,Q,WAY,SHOT,H,W,C = 2,75,5,5,10,10,640; k=5
#define QN    75
#define HWN   100
#define CN    640
#define NSUP  500                      // support descriptors per (b, group)
#define MROWS 7500                     // query patches per batch
#define NQD   (2 * MROWS)              // 15000
#define NSD   5000
#define MT    64                       // rows per workgroup
#define NTOT  512                      // padded support columns
#define BK    32

typedef __attribute__((ext_vector_type(8))) __bf16 bf16x8;
typedef __attribute__((ext_vector_type(4))) float  f32x4;

static __device__ inline unsigned short f2bf(float f) {
    unsigned int u = __float_as_uint(f);
    u += 0x7fffu + ((u >> 16) & 1u);        // RNE
    return (unsigned short)(u >> 16);
}

// ---------------------------------------------------------------------------
// Prep: one wave per descriptor. Load 640 fp32, compute inv-norm, write
// NORMALIZED bf16 into ws (q then s), fully vectorized.
// ---------------------------------------------------------------------------
__global__ __launch_bounds__(256) void prep_kernel(const float* __restrict__ q,
                                                   const float* __restrict__ s,
                                                   unsigned short* __restrict__ qbf,
                                                   unsigned short* __restrict__ sbf) {
    int wave = (blockIdx.x * 256 + threadIdx.x) >> 6;
    int lane = threadIdx.x & 63;
    if (wave >= NQD + NSD) return;
    const float* src = (wave < NQD) ? (q + (size_t)wave * CN)
                                    : (s + (size_t)(wave - NQD) * CN);
    unsigned short* dst = (wave < NQD) ? (qbf + (size_t)wave * CN)
                                       : (sbf + (size_t)(wave - NQD) * CN);
    float4 v[3];
    float ss = 0.f;
#pragma unroll
    for (int j = 0; j < 3; ++j) {
        int idx4 = lane + 64 * j;                 // 160 float4s total
        if (idx4 < CN / 4) {
            v[j] = *(const float4*)(src + idx4 * 4);
            ss = fmaf(v[j].x, v[j].x, ss);
            ss = fmaf(v[j].y, v[j].y, ss);
            ss = fmaf(v[j].z, v[j].z, ss);
            ss = fmaf(v[j].w, v[j].w, ss);
        }
    }
#pragma unroll
    for (int off = 32; off > 0; off >>= 1)
        ss += __shfl_xor(ss, off, 64);
    float inv = rsqrtf(ss);
#pragma unroll
    for (int j = 0; j < 3; ++j) {
        int idx4 = lane + 64 * j;
        if (idx4 < CN / 4) {
            ushort4 o;
            o.x = f2bf(v[j].x * inv);
            o.y = f2bf(v[j].y * inv);
            o.z = f2bf(v[j].z * inv);
            o.w = f2bf(v[j].w * inv);
            *(ushort4*)(dst + idx4 * 4) = o;
        }
    }
}

// ---------------------------------------------------------------------------
// Fused MFMA GEMM + top-5 + reduce.
// grid = (ceil(7500/64), way=5, b=2), block = 256 (4 waves).
// Workgroup: 64 rows x 512 cols, K=640. Wave owns cols [wid*128, +128).
// 16x16x32 bf16 MFMA; acc[4 mtiles][8 ntiles] of f32x4.
// ---------------------------------------------------------------------------
__global__ __launch_bounds__(256, 2) void mfma_kernel(const unsigned short* __restrict__ qbf,
                                                      const unsigned short* __restrict__ sbf,
                                                      float* __restrict__ out) {
    __shared__ __align__(16) char smem[36864];      // A: 4 KB, B: 32 KB
    unsigned short* Alds = (unsigned short*)smem;          // [64][32]
    unsigned short* Blds = (unsigned short*)(smem + 4096); // [512][32]
    float*          Cst  = (float*)smem;                   // epilogue [16][516]

    const int t    = threadIdx.x;
    const int lane = t & 63;
    const int wid  = t >> 6;
    const int b    = blockIdx.z;
    const int g    = blockIdx.y;
    const int r0   = blockIdx.x * MT;

    const size_t qbase = (size_t)b * MROWS * CN;
    const size_t sbase = (size_t)(b * 25 + g * 5) * HWN * CN;  // group = 500 contiguous descs

    f32x4 acc[4][8];
#pragma unroll
    for (int mt = 0; mt < 4; ++mt)
#pragma unroll
        for (int nt = 0; nt < 8; ++nt)
            acc[mt][nt] = (f32x4)0.f;

    // staging assignments
    const int a_row = t >> 2, a_g = t & 3;                 // A: (row, 16B-granule)
    int arow_l = r0 + a_row; if (arow_l > MROWS - 1) arow_l = MROWS - 1;
    const unsigned short* aptr = qbf + qbase + (size_t)arow_l * CN + a_g * 8;
    const int b_col0 = t >> 2, b_g = t & 3;                // B: (col base, granule)

    const int q_  = lane >> 4;     // k-quad
    const int lr  = lane & 15;     // row/col within tile

    for (int k0 = 0; k0 < CN; k0 += BK) {
        __syncthreads();
        // stage A tile: 64 rows x 32 k
        *(uint4*)(Alds + a_row * 32 + a_g * 8) = *(const uint4*)(aptr + k0);
        // stage B tile: 512 cols x 32 k
#pragma unroll
        for (int i = 0; i < 8; ++i) {
            int col  = b_col0 + 64 * i;
            int colc = (col < NSUP) ? col : (NSUP - 1);
            *(uint4*)(Blds + col * 32 + b_g * 8) =
                *(const uint4*)(sbf + sbase + (size_t)colc * CN + k0 + b_g * 8);
        }
        __syncthreads();

        bf16x8 af[4];
#pragma unroll
        for (int mt = 0; mt < 4; ++mt)
            af[mt] = *(const bf16x8*)(Alds + (mt * 16 + lr) * 32 + q_ * 8);
#pragma unroll
        for (int nt = 0; nt < 8; ++nt) {
            bf16x8 bfr = *(const bf16x8*)(Blds + (wid * 128 + nt * 16 + lr) * 32 + q_ * 8);
#pragma unroll
            for (int mt = 0; mt < 4; ++mt)
                acc[mt][nt] = __builtin_amdgcn_mfma_f32_16x16x32_bf16(af[mt], bfr, acc[mt][nt], 0, 0, 0);
        }
    }

    // ------------------ fused epilogue: per-16-row chunks ------------------
#define CE(a, b) { float hi_ = fmaxf(a, b), lo_ = fminf(a, b); a = hi_; b = lo_; }
#pragma unroll 1
    for (int mt = 0; mt < 4; ++mt) {
        __syncthreads();   // previous chunk's readers (and K-loop readers) done
#pragma unroll
        for (int nt = 0; nt < 8; ++nt)
#pragma unroll
            for (int e = 0; e < 4; ++e)
                Cst[(q_ * 4 + e) * 516 + wid * 128 + nt * 16 + lr] = acc[mt][nt][e];
        __syncthreads();

        if (t < 128) {
            int row = t >> 3, s = t & 7;
            float t0 = -3.4e38f, t1 = -3.4e38f, t2 = -3.4e38f, t3 = -3.4e38f, t4 = -3.4e38f;
#pragma unroll
            for (int i = 0; i < 64; ++i) {
                int col = s + 8 * i;
                float v = (col < NSUP) ? Cst[row * 516 + col] : -3.4e38f;
                float hi;
                hi = fmaxf(t0, v); v = fminf(t0, v); t0 = hi;
                hi = fmaxf(t1, v); v = fminf(t1, v); t1 = hi;
                hi = fmaxf(t2, v); v = fminf(t2, v); t2 = hi;
                hi = fmaxf(t3, v); v = fminf(t3, v); t3 = hi;
                hi = fmaxf(t4, v); v = fminf(t4, v); t4 = hi;
            }
            // butterfly merge across the row's 8 scanner threads
#pragma unroll
            for (int d = 1; d < 8; d <<= 1) {
                float b0 = __shfl_xor(t0, d, 64);
                float b1 = __shfl_xor(t1, d, 64);
                float b2 = __shfl_xor(t2, d, 64);
                float b3 = __shfl_xor(t3, d, 64);
                float b4 = __shfl_xor(t4, d, 64);
                t0 = fmaxf(t0, b4); t1 = fmaxf(t1, b3); t2 = fmaxf(t2, b2);
                t3 = fmaxf(t3, b1); t4 = fmaxf(t4, b0);
                // odd-even transposition sort (desc), 5 passes
                CE(t0, t1); CE(t2, t3);
                CE(t1, t2); CE(t3, t4);
                CE(t0, t1); CE(t2, t3);
                CE(t1, t2); CE(t3, t4);
                CE(t0, t1); CE(t2, t3);
            }
            if (s == 0) {
                int patch = r0 + mt * 16 + row;
                if (patch < MROWS) {
                    int qi = patch / HWN;
                    atomicAdd(&out[(b * QN + qi) * 5 + g], (t0 + t1 + t2 + t3 + t4) * 0.2f);
                }
            }
        }
    }
#undef CE
}

// ---------------------------------------------------------------------------
// Fallback (round-1 correct path) if ws is too small for bf16 copies.
// ---------------------------------------------------------------------------
__global__ __launch_bounds__(256) void norm_kernel(const float* __restrict__ q,
                                                   const float* __restrict__ s,
                                                   float* __restrict__ qinv,
                                                   float* __restrict__ sinv) {
    int wave = (blockIdx.x * 256 + threadIdx.x) >> 6;
    int lane = threadIdx.x & 63;
    if (wave >= NQD + NSD) return;
    const float* base = (wave < NQD) ? (q + (size_t)wave * CN)
                                     : (s + (size_t)(wave - NQD) * CN);
    float ss = 0.f;
#pragma unroll
    for (int i = 0; i < CN / 64; ++i) { float v = base[lane + 64 * i]; ss = fmaf(v, v, ss); }
#pragma unroll
    for (int off = 32; off > 0; off >>= 1) ss += __shfl_down(ss, off, 64);
    if (lane == 0) {
        float inv = rsqrtf(ss);
        if (wave < NQD) qinv[wave] = inv; else sinv[wave - NQD] = inv;
    }
}

__global__ __launch_bounds__(256) void score_kernel(const float* __restrict__ qd,
                                                    const float* __restrict__ sd,
                                                    const float* __restrict__ qinv,
                                                    const float* __restrict__ sinv,
                                                    float* __restrict__ out) {
    int gp = blockIdx.x * 256 + threadIdx.x;
    int g  = blockIdx.y;
    if (gp >= NQD) return;
    int b = gp / MROWS, rem = gp - b * MROWS, qi = rem / HWN;
    const float* aptr = qd + (size_t)gp * CN;
    int sd0 = (b * 5 + g) * NSUP;
    const float* sb = sd + (size_t)sd0 * CN;
    const float* siv = sinv + sd0;
    float qs = qinv[gp];
    float t0 = -3.4e38f, t1 = -3.4e38f, t2 = -3.4e38f, t3 = -3.4e38f, t4 = -3.4e38f;
    for (int jc = 0; jc < NSUP; jc += 25) {
        float acc[25];
#pragma unroll
        for (int jj = 0; jj < 25; ++jj) acc[jj] = 0.f;
        for (int kc = 0; kc < CN; kc += 4) {
            float4 a4 = *(const float4*)(aptr + kc);
#pragma unroll
            for (int jj = 0; jj < 25; ++jj) {
                const float* sp = sb + (size_t)(jc + jj) * CN + kc;
                acc[jj] = fmaf(a4.x, sp[0], acc[jj]);
                acc[jj] = fmaf(a4.y, sp[1], acc[jj]);
                acc[jj] = fmaf(a4.z, sp[2], acc[jj]);
                acc[jj] = fmaf(a4.w, sp[3], acc[jj]);
            }
        }
#pragma unroll
        for (int jj = 0; jj < 25; ++jj) {
            float v = acc[jj] * qs * siv[jc + jj], hi;
            hi = fmaxf(t0, v); v = fminf(t0, v); t0 = hi;
            hi = fmaxf(t1, v); v = fminf(t1, v); t1 = hi;
            hi = fmaxf(t2, v); v = fminf(t2, v); t2 = hi;
            hi = fmaxf(t3, v); v = fminf(t3, v); t3 = hi;
            hi = fmaxf(t4, v); v = fminf(t4, v); t4 = hi;
        }
    }
    atomicAdd(&out[(b * QN + qi) * 5 + g], (t0 + t1 + t2 + t3 + t4) * 0.2f);
}

extern "C" void kernel_launch(void* const* d_in, const int* in_sizes, int n_in,
                              void* d_out, int out_size, void* d_ws, size_t ws_size,
                              hipStream_t stream) {
    const float* in1 = (const float*)d_in[0];
    const float* in2 = (const float*)d_in[1];
    float* out = (float*)d_out;

    hipMemsetAsync(d_out, 0, (size_t)out_size * sizeof(float), stream);

    const size_t need = ((size_t)NQD + NSD) * CN * sizeof(unsigned short); // 25.6 MB
    if (ws_size >= need) {
        unsigned short* qbf = (unsigned short*)d_ws;
        unsigned short* sbf = qbf + (size_t)NQD * CN;
        prep_kernel<<<dim3((NQD + NSD) / 4), 256, 0, stream>>>(in1, in2, qbf, sbf);
        dim3 grid((MROWS + MT - 1) / MT, 5, 2);   // (118, 5, 2)
        mfma_kernel<<<grid, 256, 0, stream>>>(qbf, sbf, out);
    } else {
        float* qinv = (float*)d_ws;
        float* sinv = qinv + NQD;
        norm_kernel<<<dim3((NQD + NSD) / 4), 256, 0, stream>>>(in1, in2, qinv, sinv);
        dim3 grid((NQD + 255) / 256, 5);
        score_kernel<<<grid, 256, 0, stream>>>(in1, in2, qinv, sinv, out);
    }
}

// Round 3
// 238.905 us; speedup vs baseline: 27.4400x; 2.6374x over previous
//
#include <hip/hip_runtime.h>

// MetaBaseline: B,Q,WAY,SHOT,H,W,C = 2,75,5,5,10,10,640; k=5
#define QN    75
#define HWN   100
#define CN    640
#define NSUP  500                      // support descriptors per (b, group)
#define MROWS 7500                     // query patches per batch
#define NQD   (2 * MROWS)              // 15000
#define NSD   5000
#define MT    64                       // rows per workgroup
#define BK    32
#define CSTRIDE 528                    // epilogue C stride (dwords); 528%32==16 -> 2-way scan

typedef __attribute__((ext_vector_type(8))) __bf16 bf16x8;
typedef __attribute__((ext_vector_type(4))) float  f32x4;

static __device__ inline unsigned short f2bf(float f) {
    unsigned int u = __float_as_uint(f);
    u += 0x7fffu + ((u >> 16) & 1u);        // RNE
    return (unsigned short)(u >> 16);
}

// ---------------------------------------------------------------------------
// Prep: one wave per descriptor. Load 640 fp32, compute inv-norm, write
// NORMALIZED bf16 into ws (q then s), fully vectorized.
// ---------------------------------------------------------------------------
__global__ __launch_bounds__(256) void prep_kernel(const float* __restrict__ q,
                                                   const float* __restrict__ s,
                                                   unsigned short* __restrict__ qbf,
                                                   unsigned short* __restrict__ sbf) {
    int wave = (blockIdx.x * 256 + threadIdx.x) >> 6;
    int lane = threadIdx.x & 63;
    if (wave >= NQD + NSD) return;
    const float* src = (wave < NQD) ? (q + (size_t)wave * CN)
                                    : (s + (size_t)(wave - NQD) * CN);
    unsigned short* dst = (wave < NQD) ? (qbf + (size_t)wave * CN)
                                       : (sbf + (size_t)(wave - NQD) * CN);
    float4 v[3];
    float ss = 0.f;
#pragma unroll
    for (int j = 0; j < 3; ++j) {
        int idx4 = lane + 64 * j;                 // 160 float4s total
        if (idx4 < CN / 4) {
            v[j] = *(const float4*)(src + idx4 * 4);
            ss = fmaf(v[j].x, v[j].x, ss);
            ss = fmaf(v[j].y, v[j].y, ss);
            ss = fmaf(v[j].z, v[j].z, ss);
            ss = fmaf(v[j].w, v[j].w, ss);
        }
    }
#pragma unroll
    for (int off = 32; off > 0; off >>= 1)
        ss += __shfl_xor(ss, off, 64);
    float inv = rsqrtf(ss);
#pragma unroll
    for (int j = 0; j < 3; ++j) {
        int idx4 = lane + 64 * j;
        if (idx4 < CN / 4) {
            ushort4 o;
            o.x = f2bf(v[j].x * inv);
            o.y = f2bf(v[j].y * inv);
            o.z = f2bf(v[j].z * inv);
            o.w = f2bf(v[j].w * inv);
            *(ushort4*)(dst + idx4 * 4) = o;
        }
    }
}

// ---------------------------------------------------------------------------
// Fused MFMA GEMM + top-5 + reduce.
// grid = (ceil(7500/64), way=5, b=2), block = 256 (4 waves).
// Workgroup: 64 rows x 512 cols, K=640. Wave owns cols [wid*128, +128).
// 16x16x32 bf16 MFMA; acc[4 mtiles][8 ntiles] of f32x4 (AGPRs).
// LDS granule XOR-swizzle: granule g of row r lives at slot g^((r>>1)&3),
// making the b128 fragment reads 2-way (free) instead of 4-way.
// ---------------------------------------------------------------------------
__global__ __launch_bounds__(256, 2) void mfma_kernel(const unsigned short* __restrict__ qbf,
                                                      const unsigned short* __restrict__ sbf,
                                                      float* __restrict__ out) {
    __shared__ __align__(16) char smem[36864];      // A: 4 KB, B: 32 KB; Cst: 33.8 KB
    unsigned short* Alds = (unsigned short*)smem;          // [64][32] + swizzle
    unsigned short* Blds = (unsigned short*)(smem + 4096); // [512][32] + swizzle
    float*          Cst  = (float*)smem;                   // epilogue [16][CSTRIDE]

    const int t    = threadIdx.x;
    const int lane = t & 63;
    const int wid  = t >> 6;
    const int b    = blockIdx.z;
    const int g    = blockIdx.y;
    const int r0   = blockIdx.x * MT;

    const size_t qbase = (size_t)b * MROWS * CN;
    const size_t sbase = (size_t)(b * 25 + g * 5) * HWN * CN;  // group = 500 contiguous descs

    f32x4 acc[4][8];
#pragma unroll
    for (int mt = 0; mt < 4; ++mt)
#pragma unroll
        for (int nt = 0; nt < 8; ++nt)
            acc[mt][nt] = (f32x4)0.f;

    // staging assignments
    const int a_row = t >> 2, a_g = t & 3;                 // (row, 16B source granule)
    const int slot  = a_g ^ ((a_row >> 1) & 3);            // swizzled LDS slot
    int arow_l = r0 + a_row; if (arow_l > MROWS - 1) arow_l = MROWS - 1;
    const unsigned short* aptr = qbf + qbase + (size_t)arow_l * CN + a_g * 8;

    const int q_  = lane >> 4;     // k-quad
    const int lr  = lane & 15;     // row/col within tile
    const int rsw = (lr >> 1) & 3; // read-side swizzle term

    for (int k0 = 0; k0 < CN; k0 += BK) {
        __syncthreads();
        // stage A tile: 64 rows x 32 k
        *(uint4*)(Alds + a_row * 32 + slot * 8) = *(const uint4*)(aptr + k0);
        // stage B tile: 512 cols x 32 k  (col base a_row, same granule/slot math)
#pragma unroll
        for (int i = 0; i < 8; ++i) {
            int col  = a_row + 64 * i;
            int colc = (col < NSUP) ? col : (NSUP - 1);
            *(uint4*)(Blds + col * 32 + slot * 8) =
                *(const uint4*)(sbf + sbase + (size_t)colc * CN + k0 + a_g * 8);
        }
        __syncthreads();

        bf16x8 af[4];
#pragma unroll
        for (int mt = 0; mt < 4; ++mt)
            af[mt] = *(const bf16x8*)(Alds + (mt * 16 + lr) * 32 + (q_ ^ rsw) * 8);
#pragma unroll
        for (int nt = 0; nt < 8; ++nt) {
            bf16x8 bfr = *(const bf16x8*)(Blds + (wid * 128 + nt * 16 + lr) * 32 + (q_ ^ rsw) * 8);
#pragma unroll
            for (int mt = 0; mt < 4; ++mt)
                acc[mt][nt] = __builtin_amdgcn_mfma_f32_16x16x32_bf16(af[mt], bfr, acc[mt][nt], 0, 0, 0);
        }
    }

    // ------------------ fused epilogue: per-16-row chunks ------------------
    // FULLY UNROLLED over mt: runtime-indexing acc[] would demote it to
    // scratch (R2: 3.2 GB of HBM writes from exactly that).
    const int erow = t >> 4;        // 0..15
    const int es   = t & 15;        // 16 scanners per row
#define CE(a, b) { float hi_ = fmaxf(a, b), lo_ = fminf(a, b); a = hi_; b = lo_; }
#pragma unroll
    for (int mt = 0; mt < 4; ++mt) {
        __syncthreads();
#pragma unroll
        for (int nt = 0; nt < 8; ++nt)
#pragma unroll
            for (int e = 0; e < 4; ++e)
                Cst[(q_ * 4 + e) * CSTRIDE + wid * 128 + nt * 16 + lr] = acc[mt][nt][e];
        __syncthreads();

        float t0 = -3.4e38f, t1 = -3.4e38f, t2 = -3.4e38f, t3 = -3.4e38f, t4 = -3.4e38f;
#pragma unroll
        for (int i = 0; i < 32; ++i) {
            int col = es + 16 * i;
            float v = (col < NSUP) ? Cst[erow * CSTRIDE + col] : -3.4e38f;
            float hi;
            hi = fmaxf(t0, v); v = fminf(t0, v); t0 = hi;
            hi = fmaxf(t1, v); v = fminf(t1, v); t1 = hi;
            hi = fmaxf(t2, v); v = fminf(t2, v); t2 = hi;
            hi = fmaxf(t3, v); v = fminf(t3, v); t3 = hi;
            hi = fmaxf(t4, v); v = fminf(t4, v); t4 = hi;
        }
        // butterfly merge across the row's 16 scanner threads (within-wave)
#pragma unroll
        for (int d = 1; d < 16; d <<= 1) {
            float b0 = __shfl_xor(t0, d, 64);
            float b1 = __shfl_xor(t1, d, 64);
            float b2 = __shfl_xor(t2, d, 64);
            float b3 = __shfl_xor(t3, d, 64);
            float b4 = __shfl_xor(t4, d, 64);
            t0 = fmaxf(t0, b4); t1 = fmaxf(t1, b3); t2 = fmaxf(t2, b2);
            t3 = fmaxf(t3, b1); t4 = fmaxf(t4, b0);
            // odd-even transposition re-sort (desc), 5 passes
            CE(t0, t1); CE(t2, t3);
            CE(t1, t2); CE(t3, t4);
            CE(t0, t1); CE(t2, t3);
            CE(t1, t2); CE(t3, t4);
            CE(t0, t1); CE(t2, t3);
        }
        if (es == 0) {
            int patch = r0 + mt * 16 + erow;
            if (patch < MROWS) {
                int qi = patch / HWN;
                atomicAdd(&out[(b * QN + qi) * 5 + g], (t0 + t1 + t2 + t3 + t4) * 0.2f);
            }
        }
    }
#undef CE
}

extern "C" void kernel_launch(void* const* d_in, const int* in_sizes, int n_in,
                              void* d_out, int out_size, void* d_ws, size_t ws_size,
                              hipStream_t stream) {
    const float* in1 = (const float*)d_in[0];
    const float* in2 = (const float*)d_in[1];
    float* out = (float*)d_out;

    hipMemsetAsync(d_out, 0, (size_t)out_size * sizeof(float), stream);

    unsigned short* qbf = (unsigned short*)d_ws;          // 15000*640 bf16
    unsigned short* sbf = qbf + (size_t)NQD * CN;         // 5000*640 bf16  (25.6 MB total)

    prep_kernel<<<dim3((NQD + NSD) / 4), 256, 0, stream>>>(in1, in2, qbf, sbf);
    dim3 grid((MROWS + MT - 1) / MT, 5, 2);   // (118, 5, 2)
    mfma_kernel<<<grid, 256, 0, stream>>>(qbf, sbf, out);
}

// Round 4
// 234.107 us; speedup vs baseline: 28.0024x; 1.0205x over previous
//
#include <hip/hip_runtime.h>

// MetaBaseline: B,Q,WAY,SHOT,H,W,C = 2,75,5,5,10,10,640; k=5
#define QN    75
#define HWN   100
#define CN    640
#define NSUP  500                      // support descriptors per (b, group)
#define MROWS 7500                     // query patches per batch
#define NQD   (2 * MROWS)              // 15000
#define NSD   5000
#define MT    64                       // rows per workgroup
#define BK    32
#define CSTRIDE 528                    // epilogue C stride (dwords); 528%32==16 -> 2-way scan

typedef __attribute__((ext_vector_type(8))) __bf16 bf16x8;
typedef __attribute__((ext_vector_type(4))) float  f32x4;

// async global->LDS DMA, 16B per lane; LDS dest = wave-uniform base + lane*16
#define GLDS(gp, lp) __builtin_amdgcn_global_load_lds(                        \
    (const __attribute__((address_space(1))) void*)(gp),                      \
    (__attribute__((address_space(3))) void*)(lp), 16, 0, 0)

static __device__ inline unsigned short f2bf(float f) {
    unsigned int u = __float_as_uint(f);
    u += 0x7fffu + ((u >> 16) & 1u);        // RNE
    return (unsigned short)(u >> 16);
}

// ---------------------------------------------------------------------------
// Prep: one wave per descriptor. Load 640 fp32, compute inv-norm, write
// NORMALIZED bf16 into ws (q then s), fully vectorized.
// ---------------------------------------------------------------------------
__global__ __launch_bounds__(256) void prep_kernel(const float* __restrict__ q,
                                                   const float* __restrict__ s,
                                                   unsigned short* __restrict__ qbf,
                                                   unsigned short* __restrict__ sbf) {
    int wave = (blockIdx.x * 256 + threadIdx.x) >> 6;
    int lane = threadIdx.x & 63;
    if (wave >= NQD + NSD) return;
    const float* src = (wave < NQD) ? (q + (size_t)wave * CN)
                                    : (s + (size_t)(wave - NQD) * CN);
    unsigned short* dst = (wave < NQD) ? (qbf + (size_t)wave * CN)
                                       : (sbf + (size_t)(wave - NQD) * CN);
    float4 v[3];
    float ss = 0.f;
#pragma unroll
    for (int j = 0; j < 3; ++j) {
        int idx4 = lane + 64 * j;                 // 160 float4s total
        if (idx4 < CN / 4) {
            v[j] = *(const float4*)(src + idx4 * 4);
            ss = fmaf(v[j].x, v[j].x, ss);
            ss = fmaf(v[j].y, v[j].y, ss);
            ss = fmaf(v[j].z, v[j].z, ss);
            ss = fmaf(v[j].w, v[j].w, ss);
        }
    }
#pragma unroll
    for (int off = 32; off > 0; off >>= 1)
        ss += __shfl_xor(ss, off, 64);
    float inv = rsqrtf(ss);
#pragma unroll
    for (int j = 0; j < 3; ++j) {
        int idx4 = lane + 64 * j;
        if (idx4 < CN / 4) {
            ushort4 o;
            o.x = f2bf(v[j].x * inv);
            o.y = f2bf(v[j].y * inv);
            o.z = f2bf(v[j].z * inv);
            o.w = f2bf(v[j].w * inv);
            *(ushort4*)(dst + idx4 * 4) = o;
        }
    }
}

// ---------------------------------------------------------------------------
// Fused MFMA GEMM + top-5 + reduce. m97-style K-loop: async global_load_lds
// (16B/lane), single LDS buffer, 2 barriers per iter.
// grid = (118, way=5, b=2), block = 256 (4 waves).
// Workgroup: 64 rows x 512 cols, K=640; wave owns cols [wid*128, +128).
// LDS granule XOR-swizzle kept by permuting SOURCE granules per lane:
// LDS slot s of row r holds source granule s ^ ((r>>1)&3); read side uses
// slot q_ ^ ((lr>>1)&3) to get granule q_. 2-way b128 conflicts (free, m136).
// ---------------------------------------------------------------------------
__global__ __launch_bounds__(256, 2) void mfma_kernel(const unsigned short* __restrict__ qbf,
                                                      const unsigned short* __restrict__ sbf,
                                                      float* __restrict__ out) {
    __shared__ __align__(16) char smem[36864];      // A: 4 KB, B: 32 KB; Cst: 33.8 KB
    unsigned short* Alds = (unsigned short*)smem;          // [64][4 slots][8]
    unsigned short* Blds = (unsigned short*)(smem + 4096); // [512][4 slots][8]
    float*          Cst  = (float*)smem;                   // epilogue [16][CSTRIDE]

    const int t    = threadIdx.x;
    const int lane = t & 63;
    const int wid  = t >> 6;
    const int b    = blockIdx.z;
    const int g    = blockIdx.y;
    const int r0   = blockIdx.x * MT;

    const size_t qbase = (size_t)b * MROWS * CN;
    const size_t sbase = (size_t)(b * 25 + g * 5) * HWN * CN;  // group = 500 contiguous descs

    f32x4 acc[4][8];
#pragma unroll
    for (int mt = 0; mt < 4; ++mt)
#pragma unroll
        for (int nt = 0; nt < 8; ++nt)
            acc[mt][nt] = (f32x4)0.f;

    // ---- async staging setup (per-lane SOURCE, wave-uniform LDS dest) ----
    const int lsub = lane >> 2;        // 0..15: row/col within 1KB chunk
    const int lg   = lane & 3;         // dest slot index (lane-fixed)

    // A: wave w stages rows [w*16, +16) -> LDS chunk at Alds + w*512 elems
    const int a_lrow = wid * 16 + lsub;
    int a_grow = r0 + a_lrow; if (a_grow > MROWS - 1) a_grow = MROWS - 1;
    const int ga = lg ^ ((a_lrow >> 1) & 3);
    const unsigned short* asrc = qbf + qbase + (size_t)a_grow * CN + ga * 8;
    unsigned short* aldst = Alds + wid * 512;   // uniform across wave

    // B: wave w stages cols [w*128, +128) as 8 chunks of 16 cols
    const int b_lcol0 = wid * 128 + lsub;
    const int gb = lg ^ ((b_lcol0 >> 1) & 3);   // +16c doesn't change ((col>>1)&3)
    const unsigned short* bsrc[8];
#pragma unroll
    for (int c = 0; c < 8; ++c) {
        int lcol = b_lcol0 + 16 * c;
        int gcol = (lcol < NSUP) ? lcol : (NSUP - 1);
        bsrc[c] = sbf + sbase + (size_t)gcol * CN + gb * 8;
    }

    const int q_  = lane >> 4;     // k-quad
    const int lr  = lane & 15;     // row/col within 16x16 tile
    const int rsw = (lr >> 1) & 3; // read-side swizzle term

    for (int k0 = 0; k0 < CN; k0 += BK) {
        __syncthreads();                      // prior ds_reads done (lgkm drain)
        GLDS(asrc + k0, aldst);
#pragma unroll
        for (int c = 0; c < 8; ++c)
            GLDS(bsrc[c] + k0, Blds + (wid * 128 + c * 16) * 32);
        __syncthreads();                      // vmcnt(0) drain -> tiles landed

        bf16x8 af[4];
#pragma unroll
        for (int mt = 0; mt < 4; ++mt)
            af[mt] = *(const bf16x8*)(Alds + (mt * 16 + lr) * 32 + (q_ ^ rsw) * 8);
#pragma unroll
        for (int nt = 0; nt < 8; ++nt) {
            bf16x8 bfr = *(const bf16x8*)(Blds + (wid * 128 + nt * 16 + lr) * 32 + (q_ ^ rsw) * 8);
#pragma unroll
            for (int mt = 0; mt < 4; ++mt)
                acc[mt][nt] = __builtin_amdgcn_mfma_f32_16x16x32_bf16(af[mt], bfr, acc[mt][nt], 0, 0, 0);
        }
    }

    // ------------------ fused epilogue: per-16-row chunks ------------------
    // FULLY UNROLLED over mt: runtime-indexing acc[] demotes it to scratch
    // (R2: 3.2 GB of HBM spill traffic from exactly that).
    const int erow = t >> 4;        // 0..15
    const int es   = t & 15;        // 16 scanners per row
#define CE(a, b) { float hi_ = fmaxf(a, b), lo_ = fminf(a, b); a = hi_; b = lo_; }
#pragma unroll
    for (int mt = 0; mt < 4; ++mt) {
        __syncthreads();
#pragma unroll
        for (int nt = 0; nt < 8; ++nt)
#pragma unroll
            for (int e = 0; e < 4; ++e)
                Cst[(q_ * 4 + e) * CSTRIDE + wid * 128 + nt * 16 + lr] = acc[mt][nt][e];
        __syncthreads();

        float t0 = -3.4e38f, t1 = -3.4e38f, t2 = -3.4e38f, t3 = -3.4e38f, t4 = -3.4e38f;
#pragma unroll
        for (int i = 0; i < 32; ++i) {
            int col = es + 16 * i;
            float v = (col < NSUP) ? Cst[erow * CSTRIDE + col] : -3.4e38f;
            float hi;
            hi = fmaxf(t0, v); v = fminf(t0, v); t0 = hi;
            hi = fmaxf(t1, v); v = fminf(t1, v); t1 = hi;
            hi = fmaxf(t2, v); v = fminf(t2, v); t2 = hi;
            hi = fmaxf(t3, v); v = fminf(t3, v); t3 = hi;
            hi = fmaxf(t4, v); v = fminf(t4, v); t4 = hi;
        }
        // butterfly merge across the row's 16 scanner threads (within-wave)
#pragma unroll
        for (int d = 1; d < 16; d <<= 1) {
            float b0 = __shfl_xor(t0, d, 64);
            float b1 = __shfl_xor(t1, d, 64);
            float b2 = __shfl_xor(t2, d, 64);
            float b3 = __shfl_xor(t3, d, 64);
            float b4 = __shfl_xor(t4, d, 64);
            t0 = fmaxf(t0, b4); t1 = fmaxf(t1, b3); t2 = fmaxf(t2, b2);
            t3 = fmaxf(t3, b1); t4 = fmaxf(t4, b0);
            // odd-even transposition re-sort (desc), 5 passes
            CE(t0, t1); CE(t2, t3);
            CE(t1, t2); CE(t3, t4);
            CE(t0, t1); CE(t2, t3);
            CE(t1, t2); CE(t3, t4);
            CE(t0, t1); CE(t2, t3);
        }
        if (es == 0) {
            int patch = r0 + mt * 16 + erow;
            if (patch < MROWS) {
                int qi = patch / HWN;
                atomicAdd(&out[(b * QN + qi) * 5 + g], (t0 + t1 + t2 + t3 + t4) * 0.2f);
            }
        }
    }
#undef CE
}

extern "C" void kernel_launch(void* const* d_in, const int* in_sizes, int n_in,
                              void* d_out, int out_size, void* d_ws, size_t ws_size,
                              hipStream_t stream) {
    const float* in1 = (const float*)d_in[0];
    const float* in2 = (const float*)d_in[1];
    float* out = (float*)d_out;

    hipMemsetAsync(d_out, 0, (size_t)out_size * sizeof(float), stream);

    unsigned short* qbf = (unsigned short*)d_ws;          // 15000*640 bf16
    unsigned short* sbf = qbf + (size_t)NQD * CN;         // 5000*640 bf16  (25.6 MB total)

    prep_kernel<<<dim3((NQD + NSD) / 4), 256, 0, stream>>>(in1, in2, qbf, sbf);
    dim3 grid((MROWS + MT - 1) / MT, 5, 2);   // (118, 5, 2)
    mfma_kernel<<<grid, 256, 0, stream>>>(qbf, sbf, out);
}

// Round 5
// 220.086 us; speedup vs baseline: 29.7864x; 1.0637x over previous
//
#include <hip/hip_runtime.h>

// MetaBaseline: B,Q,WAY,SHOT,H,W,C = 2,75,5,5,10,10,640; k=5
#define QN    75
#define HWN   100
#define CN    640
#define NSUP  500                      // support descriptors per (b, group)
#define MROWS 7500                     // query patches per batch
#define NQD   (2 * MROWS)              // 15000
#define NSD   5000
#define MT    64                       // rows per workgroup
#define BK    64                       // K-chunk (10 iterations)
#define CSTRIDE 528                    // epilogue C stride (dwords); 528%32==16 -> 2-way scan

typedef __attribute__((ext_vector_type(8))) __bf16 bf16x8;
typedef __attribute__((ext_vector_type(4))) float  f32x4;

// async global->LDS DMA, 16B per lane; LDS dest = wave-uniform base + lane*16
#define GLDS(gp, lp) __builtin_amdgcn_global_load_lds(                        \
    (const __attribute__((address_space(1))) void*)(gp),                      \
    (__attribute__((address_space(3))) void*)(lp), 16, 0, 0)

static __device__ inline unsigned short f2bf(float f) {
    unsigned int u = __float_as_uint(f);
    u += 0x7fffu + ((u >> 16) & 1u);        // RNE
    return (unsigned short)(u >> 16);
}

// ---------------------------------------------------------------------------
// Prep: one wave per descriptor. Load 640 fp32, compute inv-norm, write
// NORMALIZED bf16 into ws (q then s), fully vectorized.
// ---------------------------------------------------------------------------
__global__ __launch_bounds__(256) void prep_kernel(const float* __restrict__ q,
                                                   const float* __restrict__ s,
                                                   unsigned short* __restrict__ qbf,
                                                   unsigned short* __restrict__ sbf) {
    int wave = (blockIdx.x * 256 + threadIdx.x) >> 6;
    int lane = threadIdx.x & 63;
    if (wave >= NQD + NSD) return;
    const float* src = (wave < NQD) ? (q + (size_t)wave * CN)
                                    : (s + (size_t)(wave - NQD) * CN);
    unsigned short* dst = (wave < NQD) ? (qbf + (size_t)wave * CN)
                                       : (sbf + (size_t)(wave - NQD) * CN);
    float4 v[3];
    float ss = 0.f;
#pragma unroll
    for (int j = 0; j < 3; ++j) {
        int idx4 = lane + 64 * j;                 // 160 float4s total
        if (idx4 < CN / 4) {
            v[j] = *(const float4*)(src + idx4 * 4);
            ss = fmaf(v[j].x, v[j].x, ss);
            ss = fmaf(v[j].y, v[j].y, ss);
            ss = fmaf(v[j].z, v[j].z, ss);
            ss = fmaf(v[j].w, v[j].w, ss);
        }
    }
#pragma unroll
    for (int off = 32; off > 0; off >>= 1)
        ss += __shfl_xor(ss, off, 64);
    float inv = rsqrtf(ss);
#pragma unroll
    for (int j = 0; j < 3; ++j) {
        int idx4 = lane + 64 * j;
        if (idx4 < CN / 4) {
            ushort4 o;
            o.x = f2bf(v[j].x * inv);
            o.y = f2bf(v[j].y * inv);
            o.z = f2bf(v[j].z * inv);
            o.w = f2bf(v[j].w * inv);
            *(ushort4*)(dst + idx4 * 4) = o;
        }
    }
}

// ---------------------------------------------------------------------------
// Fused MFMA GEMM + top-5 + reduce. BK=64: 10 K-iterations (halved barrier
// drains vs BK=32 — R4 showed the kernel is drain-latency-bound, all pipes
// <16%). Single LDS buffer, 2 barriers/iter, async global_load_lds 16B/lane.
// grid = (118, way=5, b=2), block = 256 (4 waves).
// Workgroup: 64 rows x 512 cols, K=640; wave owns cols [wid*128, +128).
// LDS layout (A and B identical scheme, 128 B per row/col k-window):
//   slot s of row r holds source granule s ^ (r&7); DMA writes lane i
//   (row chunk_r0 + (i>>3), slot i&7) from source granule (i&7)^(i>>3);
//   frag reads use slot (ks*4+q_) ^ (lr&7)  -> 2-way conflicts (free, m136).
// ---------------------------------------------------------------------------
__global__ __launch_bounds__(256, 2) void mfma_kernel(const unsigned short* __restrict__ qbf,
                                                      const unsigned short* __restrict__ sbf,
                                                      float* __restrict__ out) {
    __shared__ __align__(16) char smem[73728];             // A 8 KB + B 64 KB; Cst 33.8 KB
    unsigned short* Alds = (unsigned short*)smem;          // [64 rows][64 k] swizzled
    unsigned short* Blds = (unsigned short*)(smem + 8192); // [512 cols][64 k] swizzled
    float*          Cst  = (float*)smem;                   // epilogue [16][CSTRIDE]

    const int t    = threadIdx.x;
    const int lane = t & 63;
    const int wid  = t >> 6;
    const int b    = blockIdx.z;
    const int g    = blockIdx.y;
    const int r0   = blockIdx.x * MT;

    const size_t qbase = (size_t)b * MROWS * CN;
    const size_t sbase = (size_t)(b * 25 + g * 5) * HWN * CN;  // group = 500 contiguous descs

    f32x4 acc[4][8];
#pragma unroll
    for (int mt = 0; mt < 4; ++mt)
#pragma unroll
        for (int nt = 0; nt < 8; ++nt)
            acc[mt][nt] = (f32x4)0.f;

    // ---- async staging setup (per-lane SOURCE, wave-uniform LDS dest) ----
    const int lx   = lane >> 3;          // 0..7: row/col within 1KB chunk
    const int ls   = lane & 7;           // dest slot (lane-fixed)
    const int gsrc = ls ^ lx;            // source granule for this lane

    // A: wave w stages rows [w*16, +16) as 2 chunks of 8 rows
    int ar0 = r0 + wid * 16 + lx;     if (ar0 > MROWS - 1) ar0 = MROWS - 1;
    int ar1 = r0 + wid * 16 + 8 + lx; if (ar1 > MROWS - 1) ar1 = MROWS - 1;
    const unsigned short* asrc0 = qbf + qbase + (size_t)ar0 * CN + gsrc * 8;
    const unsigned short* asrc1 = qbf + qbase + (size_t)ar1 * CN + gsrc * 8;
    char* aldst = smem + wid * 2048;     // uniform per wave

    // B: wave w stages cols [w*128, +128) as 16 chunks of 8 cols.
    // Chunks 0..13 use uniform stride c*8*CN off bsrc0; chunks 14,15 are the
    // only ones that can cross col 500 -> dedicated clamped pointers.
    const int bc = wid * 128 + lx;
    const unsigned short* bsrc0 = sbf + sbase + (size_t)bc * CN + gsrc * 8;
    int bc14 = bc + 112; if (bc14 > NSUP - 1) bc14 = NSUP - 1;
    int bc15 = bc + 120; if (bc15 > NSUP - 1) bc15 = NSUP - 1;
    const unsigned short* bsrc14 = sbf + sbase + (size_t)bc14 * CN + gsrc * 8;
    const unsigned short* bsrc15 = sbf + sbase + (size_t)bc15 * CN + gsrc * 8;
    char* bldst = smem + 8192 + wid * 16384;   // uniform per wave

    const int q_ = lane >> 4;      // k-quad
    const int lr = lane & 15;      // row/col within 16x16 tile
    const int sw = lr & 7;         // read-side swizzle term

    for (int k0 = 0; k0 < CN; k0 += BK) {
        __syncthreads();                      // prior ds_reads done
        GLDS(asrc0 + k0, aldst);
        GLDS(asrc1 + k0, aldst + 1024);
#pragma unroll
        for (int c = 0; c < 14; ++c)
            GLDS(bsrc0 + k0 + c * 8 * CN, bldst + c * 1024);
        GLDS(bsrc14 + k0, bldst + 14 * 1024);
        GLDS(bsrc15 + k0, bldst + 15 * 1024);
        __syncthreads();                      // vmcnt(0) drain -> tiles landed

#pragma unroll
        for (int ks = 0; ks < 2; ++ks) {
            const int sl = ((ks * 4 + q_) ^ sw) * 8;
            bf16x8 af[4];
#pragma unroll
            for (int mt = 0; mt < 4; ++mt)
                af[mt] = *(const bf16x8*)(Alds + (mt * 16 + lr) * 64 + sl);
#pragma unroll
            for (int nt = 0; nt < 8; ++nt) {
                bf16x8 bfr = *(const bf16x8*)(Blds + (wid * 128 + nt * 16 + lr) * 64 + sl);
#pragma unroll
                for (int mt = 0; mt < 4; ++mt)
                    acc[mt][nt] = __builtin_amdgcn_mfma_f32_16x16x32_bf16(af[mt], bfr, acc[mt][nt], 0, 0, 0);
            }
        }
    }

    // ------------------ fused epilogue: per-16-row chunks ------------------
    // FULLY UNROLLED over mt: runtime-indexing acc[] demotes it to scratch
    // (R2: 3.2 GB of HBM spill traffic from exactly that).
    const int erow = t >> 4;        // 0..15
    const int es   = t & 15;        // 16 scanners per row
#define CE(a, b) { float hi_ = fmaxf(a, b), lo_ = fminf(a, b); a = hi_; b = lo_; }
#pragma unroll
    for (int mt = 0; mt < 4; ++mt) {
        __syncthreads();
#pragma unroll
        for (int nt = 0; nt < 8; ++nt)
#pragma unroll
            for (int e = 0; e < 4; ++e)
                Cst[(q_ * 4 + e) * CSTRIDE + wid * 128 + nt * 16 + lr] = acc[mt][nt][e];
        __syncthreads();

        float t0 = -3.4e38f, t1 = -3.4e38f, t2 = -3.4e38f, t3 = -3.4e38f, t4 = -3.4e38f;
#pragma unroll
        for (int i = 0; i < 32; ++i) {
            int col = es + 16 * i;
            float v = (col < NSUP) ? Cst[erow * CSTRIDE + col] : -3.4e38f;
            float hi;
            hi = fmaxf(t0, v); v = fminf(t0, v); t0 = hi;
            hi = fmaxf(t1, v); v = fminf(t1, v); t1 = hi;
            hi = fmaxf(t2, v); v = fminf(t2, v); t2 = hi;
            hi = fmaxf(t3, v); v = fminf(t3, v); t3 = hi;
            hi = fmaxf(t4, v); v = fminf(t4, v); t4 = hi;
        }
        // butterfly merge across the row's 16 scanner threads (within-wave)
#pragma unroll
        for (int d = 1; d < 16; d <<= 1) {
            float b0 = __shfl_xor(t0, d, 64);
            float b1 = __shfl_xor(t1, d, 64);
            float b2 = __shfl_xor(t2, d, 64);
            float b3 = __shfl_xor(t3, d, 64);
            float b4 = __shfl_xor(t4, d, 64);
            t0 = fmaxf(t0, b4); t1 = fmaxf(t1, b3); t2 = fmaxf(t2, b2);
            t3 = fmaxf(t3, b1); t4 = fmaxf(t4, b0);
            // odd-even transposition re-sort (desc), 5 passes
            CE(t0, t1); CE(t2, t3);
            CE(t1, t2); CE(t3, t4);
            CE(t0, t1); CE(t2, t3);
            CE(t1, t2); CE(t3, t4);
            CE(t0, t1); CE(t2, t3);
        }
        if (es == 0) {
            int patch = r0 + mt * 16 + erow;
            if (patch < MROWS) {
                int qi = patch / HWN;
                atomicAdd(&out[(b * QN + qi) * 5 + g], (t0 + t1 + t2 + t3 + t4) * 0.2f);
            }
        }
    }
#undef CE
}

extern "C" void kernel_launch(void* const* d_in, const int* in_sizes, int n_in,
                              void* d_out, int out_size, void* d_ws, size_t ws_size,
                              hipStream_t stream) {
    const float* in1 = (const float*)d_in[0];
    const float* in2 = (const float*)d_in[1];
    float* out = (float*)d_out;

    hipMemsetAsync(d_out, 0, (size_t)out_size * sizeof(float), stream);

    unsigned short* qbf = (unsigned short*)d_ws;          // 15000*640 bf16
    unsigned short* sbf = qbf + (size_t)NQD * CN;         // 5000*640 bf16  (25.6 MB total)

    prep_kernel<<<dim3((NQD + NSD) / 4), 256, 0, stream>>>(in1, in2, qbf, sbf);
    dim3 grid((MROWS + MT - 1) / MT, 5, 2);   // (118, 5, 2)
    mfma_kernel<<<grid, 256, 0, stream>>>(qbf, sbf, out);
}

// Round 6
// 164.743 us; speedup vs baseline: 39.7926x; 1.3359x over previous
//
#include <hip/hip_runtime.h>

// MetaBaseline: B,Q,WAY,SHOT,H,W,C = 2,75,5,5,10,10,640; k=5
#define QN    75
#define HWN   100
#define CN    640
#define NSUP  500                      // support descriptors per (b, group)
#define MROWS 7500                     // query patches per batch
#define NQD   (2 * MROWS)              // 15000
#define NSD   5000
#define MT    64                       // rows per workgroup
#define NT    256                      // cols per workgroup (split-N: 2 chunks)
#define BK    64                       // K-chunk (10 iterations)
#define CST   272                      // epilogue C stride (dwords); 272%32==16 -> 2-way scan

typedef __attribute__((ext_vector_type(8))) __bf16 bf16x8;
typedef __attribute__((ext_vector_type(4))) float  f32x4;

// async global->LDS DMA, 16B per lane; LDS dest = wave-uniform base + lane*16
#define GLDS(gp, lp) __builtin_amdgcn_global_load_lds(                        \
    (const __attribute__((address_space(1))) void*)(gp),                      \
    (__attribute__((address_space(3))) void*)(lp), 16, 0, 0)

static __device__ inline unsigned short f2bf(float f) {
    unsigned int u = __float_as_uint(f);
    u += 0x7fffu + ((u >> 16) & 1u);        // RNE
    return (unsigned short)(u >> 16);
}

// ---------------------------------------------------------------------------
// Prep: one wave per descriptor: inv-norm, write normalized bf16 to ws.
// ---------------------------------------------------------------------------
__global__ __launch_bounds__(256) void prep_kernel(const float* __restrict__ q,
                                                   const float* __restrict__ s,
                                                   unsigned short* __restrict__ qbf,
                                                   unsigned short* __restrict__ sbf) {
    int wave = (blockIdx.x * 256 + threadIdx.x) >> 6;
    int lane = threadIdx.x & 63;
    if (wave >= NQD + NSD) return;
    const float* src = (wave < NQD) ? (q + (size_t)wave * CN)
                                    : (s + (size_t)(wave - NQD) * CN);
    unsigned short* dst = (wave < NQD) ? (qbf + (size_t)wave * CN)
                                       : (sbf + (size_t)(wave - NQD) * CN);
    float4 v[3];
    float ss = 0.f;
#pragma unroll
    for (int j = 0; j < 3; ++j) {
        int idx4 = lane + 64 * j;
        if (idx4 < CN / 4) {
            v[j] = *(const float4*)(src + idx4 * 4);
            ss = fmaf(v[j].x, v[j].x, ss);
            ss = fmaf(v[j].y, v[j].y, ss);
            ss = fmaf(v[j].z, v[j].z, ss);
            ss = fmaf(v[j].w, v[j].w, ss);
        }
    }
#pragma unroll
    for (int off = 32; off > 0; off >>= 1)
        ss += __shfl_xor(ss, off, 64);
    float inv = rsqrtf(ss);
#pragma unroll
    for (int j = 0; j < 3; ++j) {
        int idx4 = lane + 64 * j;
        if (idx4 < CN / 4) {
            ushort4 o;
            o.x = f2bf(v[j].x * inv);
            o.y = f2bf(v[j].y * inv);
            o.z = f2bf(v[j].z * inv);
            o.w = f2bf(v[j].w * inv);
            *(ushort4*)(dst + idx4 * 4) = o;
        }
    }
}

// ---------------------------------------------------------------------------
// MFMA GEMM (64x256 tile) + per-row top-5 partials.
// grid = (118 M, 2 N-chunks, 10 (b,g)), block = 256 (4 waves).
// acc[4][4] = 64 AGPRs -> ~164 total regs -> 3 waves/SIMD; LDS 40 KB ->
// 3 blocks/CU = 12 waves/CU (R3-R5 pinned at 8 waves/CU, latency-bound).
// LDS swizzle: slot s of row r holds source granule s^(r&7); frag reads use
// slot (ks*4+q_)^(lr&7) -> 2-way conflicts (free, m136).
// Each block writes sorted top-5 per row to part[((bg*7500+row)*2+nc)*5].
// ---------------------------------------------------------------------------
__global__ __launch_bounds__(256, 3) void mfma_kernel(const unsigned short* __restrict__ qbf,
                                                      const unsigned short* __restrict__ sbf,
                                                      float* __restrict__ part) {
    __shared__ __align__(16) char smem[40960];             // A 8 KB + B 32 KB
    unsigned short* Alds = (unsigned short*)smem;          // [64 rows][64 k] swizzled
    unsigned short* Blds = (unsigned short*)(smem + 8192); // [256 cols][64 k] swizzled
    float*          Cst  = (float*)smem;                   // epilogue [16][CST]

    const int t    = threadIdx.x;
    const int lane = t & 63;
    const int wid  = t >> 6;
    const int bg   = blockIdx.z;           // b*5+g
    const int b    = bg / 5;
    const int g    = bg % 5;
    const int nc   = blockIdx.y;           // N-chunk
    const int r0   = blockIdx.x * MT;
    const int c0   = nc * NT;

    const unsigned short* qptr = qbf + (size_t)b * MROWS * CN;            // uniform
    const unsigned short* sptr = sbf + (size_t)(b * 25 + g * 5) * HWN * CN; // uniform

    f32x4 acc[4][4];
#pragma unroll
    for (int mt = 0; mt < 4; ++mt)
#pragma unroll
        for (int nt = 0; nt < 4; ++nt)
            acc[mt][nt] = (f32x4)0.f;

    // ---- async staging setup (per-lane source offset, uniform LDS dest) ----
    const int lx   = lane >> 3;          // row/col within 8-row chunk
    const int ls   = lane & 7;           // dest slot (lane-fixed)
    const int gsrc = ls ^ lx;            // source granule for this lane

    // A: wave stages rows [wid*16, +16) as 2 chunks of 8 rows
    int ar0 = r0 + wid * 16 + lx;     if (ar0 > MROWS - 1) ar0 = MROWS - 1;
    int ar1 = ar0 + 8;                if (ar1 > MROWS - 1) ar1 = MROWS - 1;
    const int aoff0 = ar0 * CN + gsrc * 8;
    const int aoff1 = ar1 * CN + gsrc * 8;
    char* aldst = smem + wid * 2048;

    // B: wave stages cols [c0 + wid*64, +64) as 8 chunks of 8 cols (clamped)
    int boff[8];
#pragma unroll
    for (int c = 0; c < 8; ++c) {
        int col = c0 + wid * 64 + c * 8 + lx;
        if (col > NSUP - 1) col = NSUP - 1;
        boff[c] = col * CN + gsrc * 8;
    }
    char* bldst = smem + 8192 + wid * 8192;

    const int q_ = lane >> 4;      // k-quad
    const int lr = lane & 15;      // row/col within 16x16 tile
    const int sw = lr & 7;         // read-side swizzle term

    for (int k0 = 0; k0 < CN; k0 += BK) {
        __syncthreads();                      // prior ds_reads done
        GLDS(qptr + aoff0 + k0, aldst);
        GLDS(qptr + aoff1 + k0, aldst + 1024);
#pragma unroll
        for (int c = 0; c < 8; ++c)
            GLDS(sptr + boff[c] + k0, bldst + c * 1024);
        __syncthreads();                      // vmcnt(0) drain -> tiles landed

#pragma unroll
        for (int ks = 0; ks < 2; ++ks) {
            const int sl = ((ks * 4 + q_) ^ sw) * 8;
            bf16x8 af[4];
#pragma unroll
            for (int mt = 0; mt < 4; ++mt)
                af[mt] = *(const bf16x8*)(Alds + (mt * 16 + lr) * 64 + sl);
#pragma unroll
            for (int nt = 0; nt < 4; ++nt) {
                bf16x8 bfr = *(const bf16x8*)(Blds + (wid * 64 + nt * 16 + lr) * 64 + sl);
#pragma unroll
                for (int mt = 0; mt < 4; ++mt)
                    acc[mt][nt] = __builtin_amdgcn_mfma_f32_16x16x32_bf16(af[mt], bfr, acc[mt][nt], 0, 0, 0);
            }
        }
    }

    // -------- epilogue: per-16-row chunks, sorted top-5 -> partials --------
    // FULLY UNROLLED over mt (runtime acc[] index -> scratch spill; see R2).
    const int erow = t >> 4;        // 0..15
    const int es   = t & 15;        // 16 scanners per row
#define CE(a, b) { float hi_ = fmaxf(a, b), lo_ = fminf(a, b); a = hi_; b = lo_; }
#pragma unroll
    for (int mt = 0; mt < 4; ++mt) {
        __syncthreads();
#pragma unroll
        for (int nt = 0; nt < 4; ++nt)
#pragma unroll
            for (int e = 0; e < 4; ++e)
                Cst[(q_ * 4 + e) * CST + wid * 64 + nt * 16 + lr] = acc[mt][nt][e];
        __syncthreads();

        float t0 = -3.4e38f, t1 = -3.4e38f, t2 = -3.4e38f, t3 = -3.4e38f, t4 = -3.4e38f;
#pragma unroll
        for (int i = 0; i < 16; ++i) {
            int col = es + 16 * i;
            float v = (c0 + col < NSUP) ? Cst[erow * CST + col] : -3.4e38f;
            float hi;
            hi = fmaxf(t0, v); v = fminf(t0, v); t0 = hi;
            hi = fmaxf(t1, v); v = fminf(t1, v); t1 = hi;
            hi = fmaxf(t2, v); v = fminf(t2, v); t2 = hi;
            hi = fmaxf(t3, v); v = fminf(t3, v); t3 = hi;
            hi = fmaxf(t4, v); v = fminf(t4, v); t4 = hi;
        }
#pragma unroll
        for (int d = 1; d < 16; d <<= 1) {
            float b0 = __shfl_xor(t0, d, 64);
            float b1 = __shfl_xor(t1, d, 64);
            float b2 = __shfl_xor(t2, d, 64);
            float b3 = __shfl_xor(t3, d, 64);
            float b4 = __shfl_xor(t4, d, 64);
            t0 = fmaxf(t0, b4); t1 = fmaxf(t1, b3); t2 = fmaxf(t2, b2);
            t3 = fmaxf(t3, b1); t4 = fmaxf(t4, b0);
            CE(t0, t1); CE(t2, t3);
            CE(t1, t2); CE(t3, t4);
            CE(t0, t1); CE(t2, t3);
            CE(t1, t2); CE(t3, t4);
            CE(t0, t1); CE(t2, t3);
        }
        if (es == 0) {
            int patch = r0 + mt * 16 + erow;
            if (patch < MROWS) {
                float* pp = part + ((size_t)(bg * MROWS + patch) * 2 + nc) * 5;
                pp[0] = t0; pp[1] = t1; pp[2] = t2; pp[3] = t3; pp[4] = t4;
            }
        }
    }
#undef CE
}

// ---------------------------------------------------------------------------
// Merge: one wave per (b,qi,g) = 750 waves. Each lane handles patches
// lane, lane+64; top-5 of the 10 partial values (union of two sorted top-5s),
// sum/5, then wave-reduce over 100 patches; lane 0 writes out directly.
// ---------------------------------------------------------------------------
__global__ __launch_bounds__(256) void merge_kernel(const float* __restrict__ part,
                                                    float* __restrict__ out) {
    int w    = (blockIdx.x * 256 + threadIdx.x) >> 6;
    int lane = threadIdx.x & 63;
    if (w >= 750) return;
    int b  = w / 375, r = w % 375;
    int qi = r / 5,   g = r % 5;
    int bg = b * 5 + g;

    float sum = 0.f;
    for (int p = lane; p < HWN; p += 64) {
        int row = qi * HWN + p;
        const float* pp = part + (size_t)(bg * MROWS + row) * 10;
        float t0 = -3.4e38f, t1 = -3.4e38f, t2 = -3.4e38f, t3 = -3.4e38f, t4 = -3.4e38f;
#pragma unroll
        for (int j = 0; j < 10; ++j) {
            float v = pp[j], hi;
            hi = fmaxf(t0, v); v = fminf(t0, v); t0 = hi;
            hi = fmaxf(t1, v); v = fminf(t1, v); t1 = hi;
            hi = fmaxf(t2, v); v = fminf(t2, v); t2 = hi;
            hi = fmaxf(t3, v); v = fminf(t3, v); t3 = hi;
            hi = fmaxf(t4, v); v = fminf(t4, v); t4 = hi;
        }
        sum += (t0 + t1 + t2 + t3 + t4) * 0.2f;
    }
#pragma unroll
    for (int off = 32; off > 0; off >>= 1)
        sum += __shfl_xor(sum, off, 64);
    if (lane == 0) out[w] = sum;        // out[(b*75+qi)*5+g] == out[w]
}

extern "C" void kernel_launch(void* const* d_in, const int* in_sizes, int n_in,
                              void* d_out, int out_size, void* d_ws, size_t ws_size,
                              hipStream_t stream) {
    const float* in1 = (const float*)d_in[0];
    const float* in2 = (const float*)d_in[1];
    float* out = (float*)d_out;

    unsigned short* qbf  = (unsigned short*)d_ws;          // 15000*640 bf16 = 19.2 MB
    unsigned short* sbf  = qbf + (size_t)NQD * CN;         //  5000*640 bf16 =  6.4 MB
    float*          part = (float*)(sbf + (size_t)NSD * CN); // 10*7500*2*5 fp32 = 3 MB

    prep_kernel<<<dim3((NQD + NSD) / 4), 256, 0, stream>>>(in1, in2, qbf, sbf);
    dim3 grid((MROWS + MT - 1) / MT, 2, 10);   // (118, 2, 10) = 2360 blocks
    mfma_kernel<<<grid, 256, 0, stream>>>(qbf, sbf, part);
    merge_kernel<<<dim3(188), 256, 0, stream>>>(part, out);   // 750 waves
}